// Round 22
// baseline (280.099 us; speedup 1.0000x reference)
//
#include <hip/hip_runtime.h>
#include <hip/hip_fp16.h>

#define B_ 64
#define L_ 128
#define E_ 300
#define HD_ 200
#define H_ 400
#define S_ 50
#define START_ 48
#define END_ 49
#define NG_ 1600
#define BL_ 8192

// ---- ws layout (bytes) ----
#define OFF_XG   0ull                          // bf16 [8192][1600]  26,214,400
#define OFF_LSTM 26214400ull                   // bf16 [8192][400]  6,553,600 (lstm16)
#define OFF_BBF  (OFF_LSTM + 5242880ull)       // bf16 [1664][320]  1,064,960 (prep->xg, overlaid by nothing live)
#define OFF_SH   (OFF_LSTM + 13107200ull)      // max(w8 320,000 ; feats 1,638,400)
#define OFF_INV  (OFF_SH + 1638400ull)         // f32 [1600]  6,400
#define OFF_WTB  (OFF_INV + 6400ull)           // bf16 [64][400] 51,200 (wtagB)
#define OFF_BIA  (OFF_WTB + 80000ull)          // f32 [1600]  6,400
#define OFF_PART (OFF_BIA + 6400ull)           // f32 [64] per-batch partials

#define NB_T 532480    // 1664*320
// prep items = NB_T + 25600 (wtagB) + 1600 (biasC) = 559,680
// grid 2187*256 = 559,872 >= 559,680  (A' gather REMOVED — folded into xg_gemm)
#define PREP_BLOCKS 2187

typedef __attribute__((ext_vector_type(8))) short short8;
typedef __attribute__((ext_vector_type(4))) float f32x4;

__device__ __forceinline__ unsigned short f32_to_bf16(float f) {
    unsigned u = __float_as_uint(f);
    unsigned r = u + 0x7fffu + ((u >> 16) & 1u);
    return (unsigned short)(r >> 16);
}
__device__ __forceinline__ unsigned pack2bf(float a, float b) {
    return (unsigned)f32_to_bf16(a) | ((unsigned)f32_to_bf16(b) << 16);
}
__device__ __forceinline__ float bf16_to_f32(unsigned short s) {
    return __uint_as_float(((unsigned)s) << 16);
}
// 4-wide int8 dot with i32 accumulate: v_dot4_i32_i8 (fallback: manual sext).
__device__ __forceinline__ int dot4(unsigned a, unsigned b, int c) {
#if __has_builtin(__builtin_amdgcn_sdot4)
    return __builtin_amdgcn_sdot4(a, b, c, false);
#else
    c += (int)(signed char)(a)       * (int)(signed char)(b);
    c += (int)(signed char)(a >> 8)  * (int)(signed char)(b >> 8);
    c += (int)(signed char)(a >> 16) * (int)(signed char)(b >> 16);
    c += (int)(signed char)(a >> 24) * (int)(signed char)(b >> 24);
    return c;
#endif
}
// wave-uniform broadcast of lane l's value (VALU readlane; fallback shfl)
__device__ __forceinline__ float rlanef(float v, int l) {
#if __has_builtin(__builtin_amdgcn_readlane)
    return __uint_as_float(__builtin_amdgcn_readlane(__float_as_uint(v), l));
#else
    return __shfl(v, l, 64);
#endif
}

// ---------------- prep: B' weights->bf16, wtagB bf16[64][400], biasC.
// (A' gather removed — xg_gemm now gathers emb directly, as in rounds 2-9.)
__global__ void prep_kernel(const float* __restrict__ wihf, const float* __restrict__ wihb,
                            const float* __restrict__ bfc, const float* __restrict__ bbc,
                            const float* __restrict__ wtag,
                            unsigned short* __restrict__ Bbf,
                            unsigned short* __restrict__ wtagB, float* __restrict__ biasC) {
    long g = (long)blockIdx.x * 256 + threadIdx.x;
    if (g < NB_T) {
        int r = (int)(g / 320), k = (int)(g % 320);
        float v = 0.f;
        if (r < NG_ && k < E_) v = (r < 800) ? wihf[r * E_ + k] : wihb[(r - 800) * E_ + k];
        Bbf[g] = f32_to_bf16(v);
        return;
    }
    g -= NB_T;
    if (g < 25600) {   // wtagB [64][400], rows >=50 zero
        int s = (int)(g / 400), k = (int)(g % 400);
        float v = (s < S_) ? wtag[s * H_ + k] : 0.f;
        wtagB[g] = f32_to_bf16(v);
        return;
    }
    g -= 25600;
    if (g < 1600) { biasC[g] = (g < 800) ? bfc[g] : bbc[g - 800]; return; }
}

// ---------------- w_hh quant: one WAVE per row, int8 (R20 proven). Global w8 layout:
//   [dir] { chunks [j=0..11][row 0..799] uint4 at (j*800+row)*16 ; tails [row] uint2 at 153600+row*8 }
__global__ __launch_bounds__(256) void quant_kernel(const float* __restrict__ whh_f,
                                                    const float* __restrict__ whh_b,
                                                    signed char* __restrict__ w8,
                                                    float* __restrict__ invs) {
    int gw = (int)((blockIdx.x * 256 + threadIdx.x) >> 6);
    int lane = threadIdx.x & 63;
    if (gw >= 1600) return;
    int dir = gw / 800, row = gw % 800;
    const float* w = (dir ? whh_b : whh_f) + row * HD_;
    float m = 1e-20f;
    for (int k = lane; k < HD_; k += 64) m = fmaxf(m, fabsf(w[k]));
    for (int off = 32; off; off >>= 1) m = fmaxf(m, __shfl_xor(m, off));
    float s = 127.f / m;
    if (lane < 50) {
        int k0 = lane * 4;
        unsigned pk = 0;
#pragma unroll
        for (int i = 0; i < 4; ++i) {
            int v = (int)rintf(w[k0 + i] * s);
            pk |= ((unsigned)(v & 0xff)) << (8 * i);
        }
        unsigned char* base = (unsigned char*)w8 + dir * 160000;
        if (lane < 48) {
            int j = lane >> 2, wsel = lane & 3;
            *(unsigned*)(base + (size_t)(j * 800 + row) * 16 + wsel * 4) = pk;
        } else {
            *(unsigned*)(base + 153600 + (size_t)row * 8 + (lane - 48) * 4) = pk;
        }
    }
    if (lane == 0) invs[gw] = m / 16129.f;   // m/(127*127)
}

// ---------------- xg GEMM (MFMA bf16): A staged DIRECTLY from emb via words gather
// (+cvt in staging, ~8 VALU/thread/k-iter — hidden under MFMA); B from pre-converted Bbf.
__global__ __launch_bounds__(256) void xg_gemm(const int* __restrict__ words,
                                               const float* __restrict__ emb,
                                               const unsigned short* __restrict__ Bbf,
                                               const float* __restrict__ biasC,
                                               unsigned short* __restrict__ xg) {
    __shared__ unsigned short As[128 * 40];
    __shared__ unsigned short Bs[128 * 40];
    __shared__ int wlds[128];
    int tid = threadIdx.x;
    int bm = blockIdx.y * 128;
    int bn = blockIdx.x * 128;
    if (tid < 128) wlds[tid] = words[bm + tid];
    __syncthreads();
    int srow = tid >> 1, half = tid & 1;
    int lane = tid & 63, wave = tid >> 6, r16 = lane & 15, kh = lane >> 4;

    f32x4 acc[2][8];
#pragma unroll
    for (int mi = 0; mi < 2; ++mi)
#pragma unroll
        for (int ni = 0; ni < 8; ++ni) acc[mi][ni] = (f32x4){0.f, 0.f, 0.f, 0.f};

    const float* Arow = emb + (long)wlds[srow] * E_;
    const unsigned short* Br = Bbf + (long)(bn + srow) * 320;

    for (int k0 = 0; k0 < 320; k0 += 32) {
        int kb = k0 + half * 16;
#pragma unroll
        for (int j4 = 0; j4 < 2; ++j4) {
            int k = kb + 8 * j4;
            float4 va = (k < E_) ? *(const float4*)(Arow + k) : make_float4(0.f, 0.f, 0.f, 0.f);
            float4 vb = (k + 4 < E_) ? *(const float4*)(Arow + k + 4) : make_float4(0.f, 0.f, 0.f, 0.f);
            *(uint4*)&As[srow * 40 + (kb - k0) + 8 * j4] =
                make_uint4(pack2bf(va.x, va.y), pack2bf(va.z, va.w),
                           pack2bf(vb.x, vb.y), pack2bf(vb.z, vb.w));
        }
#pragma unroll
        for (int j = 0; j < 2; ++j) {
            int off = half * 16 + j * 8;
            *(uint4*)&Bs[srow * 40 + off] = *(const uint4*)(Br + k0 + off);
        }
        __syncthreads();
        short8 af[2], bfv[8];
#pragma unroll
        for (int mi = 0; mi < 2; ++mi)
            af[mi] = *(const short8*)&As[(wave * 32 + mi * 16 + r16) * 40 + kh * 8];
#pragma unroll
        for (int ni = 0; ni < 8; ++ni)
            bfv[ni] = *(const short8*)&Bs[(ni * 16 + r16) * 40 + kh * 8];
#pragma unroll
        for (int mi = 0; mi < 2; ++mi)
#pragma unroll
            for (int ni = 0; ni < 8; ++ni)
                acc[mi][ni] = __builtin_amdgcn_mfma_f32_16x16x32_bf16(af[mi], bfv[ni], acc[mi][ni], 0, 0, 0);
        __syncthreads();
    }
#pragma unroll
    for (int ni = 0; ni < 8; ++ni) {
        int g = bn + ni * 16 + r16;
        if (g < NG_) {
            float bias = biasC[g];
#pragma unroll
            for (int mi = 0; mi < 2; ++mi) {
#pragma unroll
                for (int r = 0; r < 4; ++r) {
                    int row = bm + wave * 32 + mi * 16 + kh * 4 + r;
                    xg[(long)row * NG_ + g] = f32_to_bf16(acc[mi][ni][r] + bias);
                }
            }
        }
    }
}

// ---------------- LSTM recurrence: EXACT R20 kernel (int8; empirical floor 147 us —
// invariant across 7 schedules and 2 precisions; latency-bound recurrence).
__global__ __launch_bounds__(832) void lstm_rec(const unsigned short* __restrict__ xg,
                                                const signed char* __restrict__ w8,
                                                const float* __restrict__ invs,
                                                unsigned short* __restrict__ lstm16) {
    __shared__ __align__(16) unsigned char hbuf[256];   // int8 h (200 used)
    __shared__ float a_lds[800];                        // gate activations [q*200+ko]
    int tid = threadIdx.x;
    int dir = blockIdx.x >> 6;
    int b = blockIdx.x & 63;
    bool act = tid < 800;
    int tw = act ? tid : 0;
    int q = tid / 200;   // 0=i 1=f 2=g 3=o

    const unsigned char* wbase = (const unsigned char*)w8 + dir * 160000;
    uint4 wA[12];
    uint2 wAt;
#pragma unroll
    for (int j = 0; j < 12; ++j)
        wA[j] = *(const uint4*)(wbase + (size_t)(j * 800 + tw) * 16);
    wAt = *(const uint2*)(wbase + 153600 + (size_t)tw * 8);
#pragma unroll
    for (int j = 0; j < 12; ++j)
        asm volatile("" : "+v"(wA[j].x), "+v"(wA[j].y), "+v"(wA[j].z), "+v"(wA[j].w));
    asm volatile("" : "+v"(wAt.x), "+v"(wAt.y));

    float invsc = act ? invs[dir * 800 + tid] : 0.f;
    if (tid < 64) ((unsigned*)hbuf)[tid] = 0u;   // h=0
    float c = 0.f;
    __syncthreads();

    const uint4* h4c = (const uint4*)hbuf;
    const uint2* ht2 = (const uint2*)(hbuf + 192);
    const unsigned short* xbase = xg + (long)b * L_ * NG_ + dir * 800;

    int t0 = dir ? (L_ - 1) : 0;
    float x = act ? bf16_to_f32(xbase[(long)t0 * NG_ + tid]) : 0.f;

    for (int step = 0; step < L_; ++step) {
        int t = dir ? (L_ - 1 - step) : step;
        float x_n = 0.f;
        if (act && step + 1 < L_) {
            int tn = dir ? (t - 1) : (t + 1);
            x_n = bf16_to_f32(xbase[(long)tn * NG_ + tid]);
        }
        if (act) {
            int di = 0;
#pragma unroll
            for (int j = 0; j < 12; ++j) {
                uint4 hh = h4c[j];
                di = dot4(wA[j].x, hh.x, di); di = dot4(wA[j].y, hh.y, di);
                di = dot4(wA[j].z, hh.z, di); di = dot4(wA[j].w, hh.w, di);
            }
            {
                uint2 hh = ht2[0];
                di = dot4(wAt.x, hh.x, di); di = dot4(wAt.y, hh.y, di);
            }
            float p = x + (float)di * invsc;
            float av;
            if (q == 2) {
                float e = __expf(-2.f * p);          // tanh(g)
                av = 2.f / (1.f + e) - 1.f;
            } else {
                av = 1.f / (1.f + __expf(-p));       // sigmoid (i,f,o)
            }
            a_lds[tid] = av;
        }
        __syncthreads();
        if (tid < HD_) {
            float ig = a_lds[tid];
            float fg = a_lds[200 + tid];
            float gg = a_lds[400 + tid];
            float og = a_lds[600 + tid];
            c = fg * c + ig * gg;
            float ec = __expf(-2.f * c);
            float hn = og * (2.f / (1.f + ec) - 1.f);
            ((signed char*)hbuf)[tid] = (signed char)(int)rintf(hn * 127.f);
            lstm16[((long)(b * L_ + t)) * H_ + dir * HD_ + tid] = f32_to_bf16(hn);
        }
        x = x_n;
        __syncthreads();
    }
}

// ---------------- features via MFMA (unchanged)
__global__ __launch_bounds__(256) void feat_kernel(const unsigned short* __restrict__ lstm16,
                                                   const unsigned short* __restrict__ wtagB,
                                                   const float* __restrict__ btag,
                                                   float* __restrict__ feats) {
    __shared__ unsigned short As[128 * 40];
    __shared__ unsigned short Bs[64 * 40];
    int tid = threadIdx.x;
    int bm = blockIdx.x * 128;
    int srow = tid >> 1, half = tid & 1;
    int lane = tid & 63, wave = tid >> 6, r16 = lane & 15, kh = lane >> 4;

    f32x4 acc[2][4];
#pragma unroll
    for (int mi = 0; mi < 2; ++mi)
#pragma unroll
        for (int ni = 0; ni < 4; ++ni) acc[mi][ni] = (f32x4){0.f, 0.f, 0.f, 0.f};

    const unsigned short* Ar = lstm16 + (long)(bm + srow) * 400;
    const unsigned short* Br = wtagB + (long)srow * 400;

    for (int k0 = 0; k0 < 400; k0 += 32) {
#pragma unroll
        for (int j = 0; j < 2; ++j) {
            int off = half * 16 + j * 8;
            bool kv = (k0 + off + 8 <= 400);
            uint4 z = make_uint4(0u, 0u, 0u, 0u);
            *(uint4*)&As[srow * 40 + off] = kv ? *(const uint4*)(Ar + k0 + off) : z;
            if (srow < 64)
                *(uint4*)&Bs[srow * 40 + off] = kv ? *(const uint4*)(Br + k0 + off) : z;
        }
        __syncthreads();
        short8 af[2], bfv[4];
#pragma unroll
        for (int mi = 0; mi < 2; ++mi)
            af[mi] = *(const short8*)&As[(wave * 32 + mi * 16 + r16) * 40 + kh * 8];
#pragma unroll
        for (int ni = 0; ni < 4; ++ni)
            bfv[ni] = *(const short8*)&Bs[(ni * 16 + r16) * 40 + kh * 8];
#pragma unroll
        for (int mi = 0; mi < 2; ++mi)
#pragma unroll
            for (int ni = 0; ni < 4; ++ni)
                acc[mi][ni] = __builtin_amdgcn_mfma_f32_16x16x32_bf16(af[mi], bfv[ni], acc[mi][ni], 0, 0, 0);
        __syncthreads();
    }
#pragma unroll
    for (int ni = 0; ni < 4; ++ni) {
        int g = ni * 16 + r16;
        if (g < S_) {
            float bias = btag[g];
#pragma unroll
            for (int mi = 0; mi < 2; ++mi) {
#pragma unroll
                for (int r = 0; r < 4; ++r) {
                    int row = bm + wave * 32 + mi * 16 + kh * 4 + r;
                    feats[(long)row * S_ + g] = acc[mi][ni][r] + bias;
                }
            }
        }
    }
}

// ---------------- CRF: one wave per batch, exp-factorized + fb software pipeline. (unchanged)
__global__ __launch_bounds__(64) void crf_kernel(const float* __restrict__ feats,
                                                 const float* __restrict__ trans,
                                                 const int* __restrict__ tags,
                                                 const int* __restrict__ seqlens,
                                                 float* __restrict__ part) {
    __shared__ float Tt[S_ * 53];   // Tt[j*53+i] = trans[i*50+j] = T[i][j]
    __shared__ int tg[L_];
    int lane = threadIdx.x;
    int b = blockIdx.x;
    for (int idx = lane; idx < S_ * S_; idx += 64) {
        int j = idx / S_, i = idx % S_;
        Tt[j * 53 + i] = trans[i * S_ + j];
    }
    for (int idx = lane; idx < L_; idx += 64) tg[idx] = tags[b * L_ + idx];
    int slen = seqlens[b];
    const float* fb = feats + (long)b * L_ * S_;
    __syncthreads();

    bool act = lane < S_;
    const float* Trow = Tt + (act ? lane : 0) * 53;
    float eT[S_];
#pragma unroll
    for (int i = 0; i < S_; ++i) eT[i] = __expf(Trow[i]);

    float alpha = act ? (Trow[START_] + fb[lane]) : -1e30f;
    float lal = alpha;   // valid if slen==1
    float fval = act ? fb[S_ + lane] : 0.f;   // prefetched row t=1

    for (int t = 1; t < L_; ++t) {
        float fval_n = (act && t + 1 < L_) ? fb[(t + 1) * S_ + lane] : 0.f;
        float m = alpha;
        for (int off = 32; off; off >>= 1) m = fmaxf(m, __shfl_xor(m, off));
        float p = __expf(alpha - m);
        float s0 = 0.f, s1 = 0.f, s2 = 0.f, s3 = 0.f, s4 = 0.f;
#pragma unroll
        for (int i = 0; i < S_; i += 5) {
            s0 = fmaf(rlanef(p, i),     eT[i],     s0);
            s1 = fmaf(rlanef(p, i + 1), eT[i + 1], s1);
            s2 = fmaf(rlanef(p, i + 2), eT[i + 2], s2);
            s3 = fmaf(rlanef(p, i + 3), eT[i + 3], s3);
            s4 = fmaf(rlanef(p, i + 4), eT[i + 4], s4);
        }
        float s = fmaxf(((s0 + s1) + (s2 + s3)) + s4, 1e-38f);
        float anew = m + __logf(s) + fval;
        alpha = act ? anew : -1e30f;
        if (t == slen - 1) lal = alpha;
        fval = fval_n;
    }

    float la = act ? (lal + Tt[END_ * 53 + lane]) : -1e30f;
    float m = la;
    for (int off = 32; off; off >>= 1) m = fmaxf(m, __shfl_xor(m, off));
    float e = act ? __expf(la - m) : 0.f;
    for (int off = 32; off; off >>= 1) e += __shfl_xor(e, off);
    float unl = m + __logf(e);

    float lab = 0.f;
    for (int tt = lane; tt < L_; tt += 64) {
        if (tt == 0) {
            lab += Tt[tg[0] * 53 + START_] + fb[tg[0]];
        } else if (tt < slen) {
            lab += Tt[tg[tt] * 53 + tg[tt - 1]] + fb[tt * S_ + tg[tt]];
        }
    }
    if (lane == 0) lab += Tt[END_ * 53 + tg[slen - 1]];
    for (int off = 32; off; off >>= 1) lab += __shfl_xor(lab, off);
    if (lane == 0) part[b] = unl - lab;
}

// ---------------- final: deterministic fixed-order sum of 64 partials
__global__ void fin_kernel(const float* __restrict__ part, float* __restrict__ out) {
    float s = 0.f;
    for (int i = 0; i < B_; ++i) s += part[i];
    out[0] = s;
}

extern "C" void kernel_launch(void* const* d_in, const int* in_sizes, int n_in,
                              void* d_out, int out_size, void* d_ws, size_t ws_size,
                              hipStream_t stream) {
    const int*   words = (const int*)d_in[0];
    const int*   slens = (const int*)d_in[1];
    // d_in[2] = masks: semantically (t < seq_len); not read.
    const int*   tags  = (const int*)d_in[3];
    const float* emb   = (const float*)d_in[4];
    const float* wihf  = (const float*)d_in[5];
    const float* whhf  = (const float*)d_in[6];
    const float* bf    = (const float*)d_in[7];
    const float* wihb  = (const float*)d_in[8];
    const float* whhb  = (const float*)d_in[9];
    const float* bb    = (const float*)d_in[10];
    const float* wtag  = (const float*)d_in[11];
    const float* btag  = (const float*)d_in[12];
    const float* trans = (const float*)d_in[13];

    char* ws = (char*)d_ws;
    unsigned short* xg     = (unsigned short*)(ws + OFF_XG);
    unsigned short* lstm16 = (unsigned short*)(ws + OFF_LSTM);
    unsigned short* Bbf    = (unsigned short*)(ws + OFF_BBF);  // prep -> xg (overlaid by lstm16)
    signed char*    w8     = (signed char*)(ws + OFF_SH);      // quant -> lstm
    float*          fts    = (float*)(ws + OFF_SH);            // feat -> crf (time-shared with w8)
    float*          invs   = (float*)(ws + OFF_INV);
    unsigned short* wtagB  = (unsigned short*)(ws + OFF_WTB);
    float*          biaC   = (float*)(ws + OFF_BIA);
    float*          part   = (float*)(ws + OFF_PART);
    float*          out    = (float*)d_out;

    prep_kernel<<<PREP_BLOCKS, 256, 0, stream>>>(wihf, wihb, bf, bb, wtag, Bbf, wtagB, biaC);
    quant_kernel<<<400, 256, 0, stream>>>(whhf, whhb, w8, invs);
    xg_gemm<<<dim3(13, 64), 256, 0, stream>>>(words, emb, Bbf, biaC, xg);
    lstm_rec<<<128, 832, 0, stream>>>(xg, w8, invs, lstm16);
    feat_kernel<<<64, 256, 0, stream>>>(lstm16, wtagB, btag, fts);
    crf_kernel<<<64, 64, 0, stream>>>(fts, trans, tags, slens, part);
    fin_kernel<<<1, 1, 0, stream>>>(part, out);
}

// Round 23
// 260.133 us; speedup vs baseline: 1.0768x; 1.0768x over previous
//
#include <hip/hip_runtime.h>
#include <hip/hip_fp16.h>

#define B_ 64
#define L_ 128
#define E_ 300
#define HD_ 200
#define H_ 400
#define S_ 50
#define START_ 48
#define END_ 49
#define NG_ 1600
#define BL_ 8192

// ---- ws layout (bytes) ----
#define OFF_XG   0ull                          // bf16 [8192][1600]  26,214,400
#define OFF_LSTM 26214400ull                   // bf16 [8192][400]  6,553,600 (lstm16; overlays A'/B')
#define OFF_ABF  OFF_LSTM                      // bf16 [8192][320]    5,242,880 (prep->xg)
#define OFF_BBF  (OFF_LSTM + 5242880ull)       // bf16 [1664][320]    1,064,960 (prep->xg)
#define OFF_SH   (OFF_LSTM + 13107200ull)      // w8 320,000
#define OFF_INV  (OFF_SH + 1638400ull)         // f32 [1600]  6,400
#define OFF_WTB  (OFF_INV + 6400ull)           // bf16 [64][400] 51,200 (wtagB)
#define OFF_BIA  (OFF_WTB + 80000ull)          // f32 [1600]  6,400
#define OFF_PART (OFF_BIA + 6400ull)           // f32 [64] per-batch partials

#define NA_T 2621440   // 8192*320
#define NB_T 532480    // 1664*320
// prep items = NA_T + NB_T + 25600 (wtagB) + 1600 (biasC) = 3,181,120
// grid 12427*256 = 3,181,312 >= 3,181,120
#define PREP_BLOCKS 12427

typedef __attribute__((ext_vector_type(8))) short short8;
typedef __attribute__((ext_vector_type(4))) float f32x4;

__device__ __forceinline__ unsigned short f32_to_bf16(float f) {
    unsigned u = __float_as_uint(f);
    unsigned r = u + 0x7fffu + ((u >> 16) & 1u);
    return (unsigned short)(r >> 16);
}
__device__ __forceinline__ float bf16_to_f32(unsigned short s) {
    return __uint_as_float(((unsigned)s) << 16);
}
// 4-wide int8 dot with i32 accumulate: v_dot4_i32_i8 (fallback: manual sext).
__device__ __forceinline__ int dot4(unsigned a, unsigned b, int c) {
#if __has_builtin(__builtin_amdgcn_sdot4)
    return __builtin_amdgcn_sdot4(a, b, c, false);
#else
    c += (int)(signed char)(a)       * (int)(signed char)(b);
    c += (int)(signed char)(a >> 8)  * (int)(signed char)(b >> 8);
    c += (int)(signed char)(a >> 16) * (int)(signed char)(b >> 16);
    c += (int)(signed char)(a >> 24) * (int)(signed char)(b >> 24);
    return c;
#endif
}
// wave-uniform broadcast of lane l's value (VALU readlane; fallback shfl)
__device__ __forceinline__ float rlanef(float v, int l) {
#if __has_builtin(__builtin_amdgcn_readlane)
    return __uint_as_float(__builtin_amdgcn_readlane(__float_as_uint(v), l));
#else
    return __shfl(v, l, 64);
#endif
}

// ---------------- prep: A' gather->bf16(pad 320), B' weights->bf16, wtagB bf16[64][400], biasC.
// (R22 lesson: the A' gather MUST be materialized once — xg re-reads A 13x; folding the
// 120MB-table scatter into xg cost +16us.)
__global__ void prep_kernel(const int* __restrict__ words, const float* __restrict__ emb,
                            const float* __restrict__ wihf, const float* __restrict__ wihb,
                            const float* __restrict__ bfc, const float* __restrict__ bbc,
                            const float* __restrict__ wtag,
                            unsigned short* __restrict__ Abf, unsigned short* __restrict__ Bbf,
                            unsigned short* __restrict__ wtagB, float* __restrict__ biasC) {
    long g = (long)blockIdx.x * 256 + threadIdx.x;
    if (g < NA_T) {
        int i = (int)(g / 320), k = (int)(g % 320);
        float v = (k < E_) ? emb[(long)words[i] * E_ + k] : 0.f;
        Abf[g] = f32_to_bf16(v);
        return;
    }
    g -= NA_T;
    if (g < NB_T) {
        int r = (int)(g / 320), k = (int)(g % 320);
        float v = 0.f;
        if (r < NG_ && k < E_) v = (r < 800) ? wihf[r * E_ + k] : wihb[(r - 800) * E_ + k];
        Bbf[g] = f32_to_bf16(v);
        return;
    }
    g -= NB_T;
    if (g < 25600) {   // wtagB [64][400], rows >=50 zero
        int s = (int)(g / 400), k = (int)(g % 400);
        float v = (s < S_) ? wtag[s * H_ + k] : 0.f;
        wtagB[g] = f32_to_bf16(v);
        return;
    }
    g -= 25600;
    if (g < 1600) { biasC[g] = (g < 800) ? bfc[g] : bbc[g - 800]; return; }
}

// ---------------- w_hh quant: one WAVE per row, int8. Global w8 layout (k-major chunks):
//   [dir] { chunks [j=0..11][row 0..799] uint4 at (j*800+row)*16 ; tails [row] uint2 at 153600+row*8 }
__global__ __launch_bounds__(256) void quant_kernel(const float* __restrict__ whh_f,
                                                    const float* __restrict__ whh_b,
                                                    signed char* __restrict__ w8,
                                                    float* __restrict__ invs) {
    int gw = (int)((blockIdx.x * 256 + threadIdx.x) >> 6);
    int lane = threadIdx.x & 63;
    if (gw >= 1600) return;
    int dir = gw / 800, row = gw % 800;
    const float* w = (dir ? whh_b : whh_f) + row * HD_;
    float m = 1e-20f;
    for (int k = lane; k < HD_; k += 64) m = fmaxf(m, fabsf(w[k]));
    for (int off = 32; off; off >>= 1) m = fmaxf(m, __shfl_xor(m, off));
    float s = 127.f / m;
    if (lane < 50) {
        int k0 = lane * 4;
        unsigned pk = 0;
#pragma unroll
        for (int i = 0; i < 4; ++i) {
            int v = (int)rintf(w[k0 + i] * s);
            pk |= ((unsigned)(v & 0xff)) << (8 * i);
        }
        unsigned char* base = (unsigned char*)w8 + dir * 160000;
        if (lane < 48) {
            int j = lane >> 2, wsel = lane & 3;
            *(unsigned*)(base + (size_t)(j * 800 + row) * 16 + wsel * 4) = pk;
        } else {
            *(unsigned*)(base + 153600 + (size_t)row * 8 + (lane - 48) * 4) = pk;
        }
    }
    if (lane == 0) invs[gw] = m / 16129.f;   // m/(127*127)
}

// ---------------- xg GEMM (MFMA bf16), staged from pre-converted bf16 A'/B'. (R20 exact)
__global__ __launch_bounds__(256) void xg_gemm(const unsigned short* __restrict__ Abf,
                                               const unsigned short* __restrict__ Bbf,
                                               const float* __restrict__ biasC,
                                               unsigned short* __restrict__ xg) {
    __shared__ unsigned short As[128 * 40];
    __shared__ unsigned short Bs[128 * 40];
    int tid = threadIdx.x;
    int bm = blockIdx.y * 128;
    int bn = blockIdx.x * 128;
    int srow = tid >> 1, half = tid & 1;
    int lane = tid & 63, wave = tid >> 6, r16 = lane & 15, kh = lane >> 4;

    f32x4 acc[2][8];
#pragma unroll
    for (int mi = 0; mi < 2; ++mi)
#pragma unroll
        for (int ni = 0; ni < 8; ++ni) acc[mi][ni] = (f32x4){0.f, 0.f, 0.f, 0.f};

    const unsigned short* Ar = Abf + (long)(bm + srow) * 320;
    const unsigned short* Br = Bbf + (long)(bn + srow) * 320;

    for (int k0 = 0; k0 < 320; k0 += 32) {
#pragma unroll
        for (int j = 0; j < 2; ++j) {
            int off = half * 16 + j * 8;
            *(uint4*)&As[srow * 40 + off] = *(const uint4*)(Ar + k0 + off);
            *(uint4*)&Bs[srow * 40 + off] = *(const uint4*)(Br + k0 + off);
        }
        __syncthreads();
        short8 af[2], bfv[8];
#pragma unroll
        for (int mi = 0; mi < 2; ++mi)
            af[mi] = *(const short8*)&As[(wave * 32 + mi * 16 + r16) * 40 + kh * 8];
#pragma unroll
        for (int ni = 0; ni < 8; ++ni)
            bfv[ni] = *(const short8*)&Bs[(ni * 16 + r16) * 40 + kh * 8];
#pragma unroll
        for (int mi = 0; mi < 2; ++mi)
#pragma unroll
            for (int ni = 0; ni < 8; ++ni)
                acc[mi][ni] = __builtin_amdgcn_mfma_f32_16x16x32_bf16(af[mi], bfv[ni], acc[mi][ni], 0, 0, 0);
        __syncthreads();
    }
#pragma unroll
    for (int ni = 0; ni < 8; ++ni) {
        int g = bn + ni * 16 + r16;
        if (g < NG_) {
            float bias = biasC[g];
#pragma unroll
            for (int mi = 0; mi < 2; ++mi) {
#pragma unroll
                for (int r = 0; r < 4; ++r) {
                    int row = bm + wave * 32 + mi * 16 + kh * 4 + r;
                    xg[(long)row * NG_ + g] = f32_to_bf16(acc[mi][ni][r] + bias);
                }
            }
        }
    }
}

// ---------------- LSTM recurrence: EXACT R20 kernel (empirical floor 147 us across
// 7 schedules and 2 precisions — latency-bound recurrence; frozen).
__global__ __launch_bounds__(832) void lstm_rec(const unsigned short* __restrict__ xg,
                                                const signed char* __restrict__ w8,
                                                const float* __restrict__ invs,
                                                unsigned short* __restrict__ lstm16) {
    __shared__ __align__(16) unsigned char hbuf[256];   // int8 h (200 used)
    __shared__ float a_lds[800];                        // gate activations [q*200+ko]
    int tid = threadIdx.x;
    int dir = blockIdx.x >> 6;
    int b = blockIdx.x & 63;
    bool act = tid < 800;
    int tw = act ? tid : 0;
    int q = tid / 200;   // 0=i 1=f 2=g 3=o

    const unsigned char* wbase = (const unsigned char*)w8 + dir * 160000;
    uint4 wA[12];
    uint2 wAt;
#pragma unroll
    for (int j = 0; j < 12; ++j)
        wA[j] = *(const uint4*)(wbase + (size_t)(j * 800 + tw) * 16);
    wAt = *(const uint2*)(wbase + 153600 + (size_t)tw * 8);
#pragma unroll
    for (int j = 0; j < 12; ++j)
        asm volatile("" : "+v"(wA[j].x), "+v"(wA[j].y), "+v"(wA[j].z), "+v"(wA[j].w));
    asm volatile("" : "+v"(wAt.x), "+v"(wAt.y));

    float invsc = act ? invs[dir * 800 + tid] : 0.f;
    if (tid < 64) ((unsigned*)hbuf)[tid] = 0u;   // h=0
    float c = 0.f;
    __syncthreads();

    const uint4* h4c = (const uint4*)hbuf;
    const uint2* ht2 = (const uint2*)(hbuf + 192);
    const unsigned short* xbase = xg + (long)b * L_ * NG_ + dir * 800;

    int t0 = dir ? (L_ - 1) : 0;
    float x = act ? bf16_to_f32(xbase[(long)t0 * NG_ + tid]) : 0.f;

    for (int step = 0; step < L_; ++step) {
        int t = dir ? (L_ - 1 - step) : step;
        float x_n = 0.f;
        if (act && step + 1 < L_) {
            int tn = dir ? (t - 1) : (t + 1);
            x_n = bf16_to_f32(xbase[(long)tn * NG_ + tid]);
        }
        if (act) {
            int di = 0;
#pragma unroll
            for (int j = 0; j < 12; ++j) {
                uint4 hh = h4c[j];
                di = dot4(wA[j].x, hh.x, di); di = dot4(wA[j].y, hh.y, di);
                di = dot4(wA[j].z, hh.z, di); di = dot4(wA[j].w, hh.w, di);
            }
            {
                uint2 hh = ht2[0];
                di = dot4(wAt.x, hh.x, di); di = dot4(wAt.y, hh.y, di);
            }
            float p = x + (float)di * invsc;
            float av;
            if (q == 2) {
                float e = __expf(-2.f * p);          // tanh(g)
                av = 2.f / (1.f + e) - 1.f;
            } else {
                av = 1.f / (1.f + __expf(-p));       // sigmoid (i,f,o)
            }
            a_lds[tid] = av;
        }
        __syncthreads();
        if (tid < HD_) {
            float ig = a_lds[tid];
            float fg = a_lds[200 + tid];
            float gg = a_lds[400 + tid];
            float og = a_lds[600 + tid];
            c = fg * c + ig * gg;
            float ec = __expf(-2.f * c);
            float hn = og * (2.f / (1.f + ec) - 1.f);
            ((signed char*)hbuf)[tid] = (signed char)(int)rintf(hn * 127.f);
            lstm16[((long)(b * L_ + t)) * H_ + dir * HD_ + tid] = f32_to_bf16(hn);
        }
        x = x_n;
        __syncthreads();
    }
}

// ---------------- FUSED feat+CRF: block b = batch b. Phase 1: MFMA computes the
// batch's 128x50 feature tile into LDS (no global round-trip). Phase 2: wave 0 runs
// the exp-factorized CRF from LDS. Saves a launch + feats traffic + crf load latency.
__global__ __launch_bounds__(256) void featcrf_kernel(const unsigned short* __restrict__ lstm16,
                                                      const unsigned short* __restrict__ wtagB,
                                                      const float* __restrict__ btag,
                                                      const float* __restrict__ trans,
                                                      const int* __restrict__ tags,
                                                      const int* __restrict__ seqlens,
                                                      float* __restrict__ part) {
    __shared__ unsigned short As[128 * 40];   // 10,240 B
    __shared__ unsigned short Bs[64 * 40];    //  5,120 B
    __shared__ float fts[L_ * S_];            // 25,600 B  [t][tag]
    __shared__ float Tt[S_ * 53];             // 10,600 B  Tt[j*53+i] = trans[i*50+j]
    __shared__ int tg[L_];                    //    512 B
    int tid = threadIdx.x;
    int b = blockIdx.x;
    int bm = b * 128;
    int srow = tid >> 1, half = tid & 1;
    int lane = tid & 63, wave = tid >> 6, r16 = lane & 15, kh = lane >> 4;

    // stage CRF constants (overlaps with MFMA staging)
    for (int idx = tid; idx < S_ * S_; idx += 256) {
        int j = idx / S_, i = idx % S_;
        Tt[j * 53 + i] = trans[i * S_ + j];
    }
    if (tid < L_) tg[tid] = tags[b * L_ + tid];

    f32x4 acc[2][4];
#pragma unroll
    for (int mi = 0; mi < 2; ++mi)
#pragma unroll
        for (int ni = 0; ni < 4; ++ni) acc[mi][ni] = (f32x4){0.f, 0.f, 0.f, 0.f};

    const unsigned short* Ar = lstm16 + (long)(bm + srow) * 400;
    const unsigned short* Br = wtagB + (long)srow * 400;

    for (int k0 = 0; k0 < 400; k0 += 32) {
#pragma unroll
        for (int j = 0; j < 2; ++j) {
            int off = half * 16 + j * 8;
            bool kv = (k0 + off + 8 <= 400);
            uint4 z = make_uint4(0u, 0u, 0u, 0u);
            *(uint4*)&As[srow * 40 + off] = kv ? *(const uint4*)(Ar + k0 + off) : z;
            if (srow < 64)
                *(uint4*)&Bs[srow * 40 + off] = kv ? *(const uint4*)(Br + k0 + off) : z;
        }
        __syncthreads();
        short8 af[2], bfv[4];
#pragma unroll
        for (int mi = 0; mi < 2; ++mi)
            af[mi] = *(const short8*)&As[(wave * 32 + mi * 16 + r16) * 40 + kh * 8];
#pragma unroll
        for (int ni = 0; ni < 4; ++ni)
            bfv[ni] = *(const short8*)&Bs[(ni * 16 + r16) * 40 + kh * 8];
#pragma unroll
        for (int mi = 0; mi < 2; ++mi)
#pragma unroll
            for (int ni = 0; ni < 4; ++ni)
                acc[mi][ni] = __builtin_amdgcn_mfma_f32_16x16x32_bf16(af[mi], bfv[ni], acc[mi][ni], 0, 0, 0);
        __syncthreads();
    }
#pragma unroll
    for (int ni = 0; ni < 4; ++ni) {
        int g = ni * 16 + r16;
        if (g < S_) {
            float bias = btag[g];
#pragma unroll
            for (int mi = 0; mi < 2; ++mi) {
#pragma unroll
                for (int r = 0; r < 4; ++r) {
                    int row = wave * 32 + mi * 16 + kh * 4 + r;   // local 0..127
                    fts[row * S_ + g] = acc[mi][ni][r] + bias;
                }
            }
        }
    }
    __syncthreads();

    // ---- phase 2: CRF on wave 0 (fb from LDS) ----
    if (tid >= 64) return;
    int slen = seqlens[b];
    bool act = lane < S_;
    const float* Trow = Tt + (act ? lane : 0) * 53;
    float eT[S_];
#pragma unroll
    for (int i = 0; i < S_; ++i) eT[i] = __expf(Trow[i]);

    float alpha = act ? (Trow[START_] + fts[lane]) : -1e30f;
    float lal = alpha;   // valid if slen==1

    for (int t = 1; t < L_; ++t) {
        float fval = act ? fts[t * S_ + lane] : 0.f;
        float m = alpha;
        for (int off = 32; off; off >>= 1) m = fmaxf(m, __shfl_xor(m, off));
        float p = __expf(alpha - m);
        float s0 = 0.f, s1 = 0.f, s2 = 0.f, s3 = 0.f, s4 = 0.f;
#pragma unroll
        for (int i = 0; i < S_; i += 5) {
            s0 = fmaf(rlanef(p, i),     eT[i],     s0);
            s1 = fmaf(rlanef(p, i + 1), eT[i + 1], s1);
            s2 = fmaf(rlanef(p, i + 2), eT[i + 2], s2);
            s3 = fmaf(rlanef(p, i + 3), eT[i + 3], s3);
            s4 = fmaf(rlanef(p, i + 4), eT[i + 4], s4);
        }
        float s = fmaxf(((s0 + s1) + (s2 + s3)) + s4, 1e-38f);
        float anew = m + __logf(s) + fval;
        alpha = act ? anew : -1e30f;
        if (t == slen - 1) lal = alpha;
    }

    float la = act ? (lal + Tt[END_ * 53 + lane]) : -1e30f;
    float m = la;
    for (int off = 32; off; off >>= 1) m = fmaxf(m, __shfl_xor(m, off));
    float e = act ? __expf(la - m) : 0.f;
    for (int off = 32; off; off >>= 1) e += __shfl_xor(e, off);
    float unl = m + __logf(e);

    float lab = 0.f;
    for (int tt = lane; tt < L_; tt += 64) {
        if (tt == 0) {
            lab += Tt[tg[0] * 53 + START_] + fts[tg[0]];
        } else if (tt < slen) {
            lab += Tt[tg[tt] * 53 + tg[tt - 1]] + fts[tt * S_ + tg[tt]];
        }
    }
    if (lane == 0) lab += Tt[END_ * 53 + tg[slen - 1]];
    for (int off = 32; off; off >>= 1) lab += __shfl_xor(lab, off);
    if (lane == 0) part[b] = unl - lab;
}

// ---------------- final: deterministic fixed-order sum of 64 partials
__global__ void fin_kernel(const float* __restrict__ part, float* __restrict__ out) {
    float s = 0.f;
    for (int i = 0; i < B_; ++i) s += part[i];
    out[0] = s;
}

extern "C" void kernel_launch(void* const* d_in, const int* in_sizes, int n_in,
                              void* d_out, int out_size, void* d_ws, size_t ws_size,
                              hipStream_t stream) {
    const int*   words = (const int*)d_in[0];
    const int*   slens = (const int*)d_in[1];
    // d_in[2] = masks: semantically (t < seq_len); not read.
    const int*   tags  = (const int*)d_in[3];
    const float* emb   = (const float*)d_in[4];
    const float* wihf  = (const float*)d_in[5];
    const float* whhf  = (const float*)d_in[6];
    const float* bf    = (const float*)d_in[7];
    const float* wihb  = (const float*)d_in[8];
    const float* whhb  = (const float*)d_in[9];
    const float* bb    = (const float*)d_in[10];
    const float* wtag  = (const float*)d_in[11];
    const float* btag  = (const float*)d_in[12];
    const float* trans = (const float*)d_in[13];

    char* ws = (char*)d_ws;
    unsigned short* xg     = (unsigned short*)(ws + OFF_XG);
    unsigned short* lstm16 = (unsigned short*)(ws + OFF_LSTM);
    unsigned short* Abf    = (unsigned short*)(ws + OFF_ABF);  // prep -> xg (overlaid by lstm16)
    unsigned short* Bbf    = (unsigned short*)(ws + OFF_BBF);  // prep -> xg (overlaid by lstm16)
    signed char*    w8     = (signed char*)(ws + OFF_SH);      // quant -> lstm
    float*          invs   = (float*)(ws + OFF_INV);
    unsigned short* wtagB  = (unsigned short*)(ws + OFF_WTB);
    float*          biaC   = (float*)(ws + OFF_BIA);
    float*          part   = (float*)(ws + OFF_PART);
    float*          out    = (float*)d_out;

    prep_kernel<<<PREP_BLOCKS, 256, 0, stream>>>(words, emb, wihf, wihb, bf, bb,
                                                 wtag, Abf, Bbf, wtagB, biaC);
    quant_kernel<<<400, 256, 0, stream>>>(whhf, whhb, w8, invs);
    xg_gemm<<<dim3(13, 64), 256, 0, stream>>>(Abf, Bbf, biaC, xg);
    lstm_rec<<<128, 832, 0, stream>>>(xg, w8, invs, lstm16);
    featcrf_kernel<<<64, 256, 0, stream>>>(lstm16, wtagB, btag, trans, tags, slens, part);
    fin_kernel<<<1, 1, 0, stream>>>(part, out);
}